// Round 10
// baseline (198.163 us; speedup 1.0000x reference)
//
#include <hip/hip_runtime.h>
#include <hip/hip_cooperative_groups.h>

namespace cg = cooperative_groups;

#define N_NODES 8192
#define WPR 256      // 32-bit words per bitmap row (8192 bits)
#define C 64
#define CAP 512      // per-row neighbor-list capacity (avg degree ~32)
#define MAXBLK 1024  // cap on cooperative grid

// ===========================================================================
// Shared per-phase logic (used by both the fused coop kernel and fallbacks).
// FP order is IDENTICAL in both paths => bit-identical outputs.
// ===========================================================================

// --- phase C body: one wave, one row: popcount -> dinv -> prescaled gemm ---
__device__ __forceinline__ void row_deg_gemm(int r, int lane,
        const unsigned* __restrict__ bitmap, const float* __restrict__ x,
        const float* __restrict__ Wt, float* __restrict__ ys) {
    const uint4* row = (const uint4*)(bitmap + (size_t)r * WPR);
    uint4 v = row[lane];
    int cnt = __popc(v.x) + __popc(v.y) + __popc(v.z) + __popc(v.w);
#pragma unroll
    for (int off = 32; off; off >>= 1) cnt += __shfl_down(cnt, off);
    int total = __shfl(cnt, 0);
    // +1 = added eye; a self-loop bit is already in the popcount (diag 2.0),
    // matching the reference.
    float dr = rsqrtf((float)(total + 1));
    const float* xr = x + (size_t)r * C;
    float acc = 0.0f;
#pragma unroll
    for (int k = 0; k < C; ++k) acc += xr[k] * Wt[k * C + lane];
    ys[(size_t)r * C + lane] = dr * acc;
}

// --- phase D body: one wave, one row: scan -> list -> 8-way gather ---------
__device__ __forceinline__ void row_spmm(int r, int lane,
        const unsigned* __restrict__ bitmap, const float* __restrict__ ys,
        float bl, unsigned short* __restrict__ L, float* __restrict__ out) {
    const uint4* row = (const uint4*)(bitmap + (size_t)r * WPR);
    uint4 v = row[lane];
    int myc = __popc(v.x) + __popc(v.y) + __popc(v.z) + __popc(v.w);
    int pre = myc;   // inclusive prefix sum over the wave
#pragma unroll
    for (int d = 1; d < 64; d <<= 1) {
        int t = __shfl_up(pre, d);
        if (lane >= d) pre += t;
    }
    int total = __shfl(pre, 63);
    int woff = pre - myc;
    float dr = rsqrtf((float)(total + 1));
    float acc = ys[(size_t)r * C + lane];   // eye term (ys is dinv-prescaled)
    if (total <= CAP) {
        int base = lane * 128;
        unsigned bits;
        bits = v.x; while (bits) { L[woff++] = (unsigned short)(base       + __builtin_ctz(bits)); bits &= bits - 1; }
        bits = v.y; while (bits) { L[woff++] = (unsigned short)(base + 32  + __builtin_ctz(bits)); bits &= bits - 1; }
        bits = v.z; while (bits) { L[woff++] = (unsigned short)(base + 64  + __builtin_ctz(bits)); bits &= bits - 1; }
        bits = v.w; while (bits) { L[woff++] = (unsigned short)(base + 96  + __builtin_ctz(bits)); bits &= bits - 1; }
        // no barrier: L is wave-private
        float a0=0.f,a1=0.f,a2=0.f,a3=0.f,a4=0.f,a5=0.f,a6=0.f,a7=0.f;
        int i = 0;
        for (; i + 8 <= total; i += 8) {
            int c0=L[i],  c1=L[i+1],c2=L[i+2],c3=L[i+3];
            int c4=L[i+4],c5=L[i+5],c6=L[i+6],c7=L[i+7];
            a0 += ys[(size_t)c0 * C + lane];
            a1 += ys[(size_t)c1 * C + lane];
            a2 += ys[(size_t)c2 * C + lane];
            a3 += ys[(size_t)c3 * C + lane];
            a4 += ys[(size_t)c4 * C + lane];
            a5 += ys[(size_t)c5 * C + lane];
            a6 += ys[(size_t)c6 * C + lane];
            a7 += ys[(size_t)c7 * C + lane];
        }
        for (; i < total; ++i) acc += ys[(size_t)L[i] * C + lane];
        acc += ((a0 + a1) + (a2 + a3)) + ((a4 + a5) + (a6 + a7));
    } else {
        // fallback: serial bitmap re-scan (correct for any degree)
        for (int w4i = 0; w4i < WPR / 4; ++w4i) {
            uint4 vv = row[w4i];
            int base = w4i * 128;
            unsigned bits;
            bits = vv.x; while (bits) { int c = base       + __builtin_ctz(bits); bits &= bits - 1; acc += ys[(size_t)c * C + lane]; }
            bits = vv.y; while (bits) { int c = base + 32  + __builtin_ctz(bits); bits &= bits - 1; acc += ys[(size_t)c * C + lane]; }
            bits = vv.z; while (bits) { int c = base + 64  + __builtin_ctz(bits); bits &= bits - 1; acc += ys[(size_t)c * C + lane]; }
            bits = vv.w; while (bits) { int c = base + 96  + __builtin_ctz(bits); bits &= bits - 1; acc += ys[(size_t)c * C + lane]; }
        }
    }
    out[(size_t)r * C + lane] = dr * acc + bl;
}

// ===========================================================================
// Cooperative fused kernel: 4 grid-stride phases, 3 grid syncs. Works at ANY
// grid size (phase D re-scans the bitmap; no cross-phase LDS dependence).
// LDS: Wt 16KB + list 4KB = 20KB.
// ===========================================================================
__global__ __launch_bounds__(256, 4) void gcn_fused(
    const float* __restrict__ x, const int* __restrict__ e, int E,
    const float* __restrict__ W, const float* __restrict__ bias,
    unsigned* __restrict__ bitmap, float* __restrict__ ys,
    float* __restrict__ out)
{
    cg::grid_group grid = cg::this_grid();
    __shared__ float Wt[C * C];
    __shared__ unsigned short list[4][CAP];
    const int tid = threadIdx.x, wave = tid >> 6, lane = tid & 63;
    const int gthreads = gridDim.x * 256;
    const int gwaves = gridDim.x * 4;
    const int gw = blockIdx.x * 4 + wave;

    // A: zero bitmap (uint4 grid-stride) + stage W transposed in LDS
    {
        uint4* bm4 = (uint4*)bitmap;
        for (int i = blockIdx.x * 256 + tid; i < N_NODES * WPR / 4; i += gthreads)
            bm4[i] = make_uint4(0u, 0u, 0u, 0u);
        for (int i = tid; i < C * C; i += 256) {
            int o = i >> 6, k = i & 63;
            Wt[k * C + o] = W[i];
        }
    }
    grid.sync();

    // B: edge scatter — NON-RETURNING atomicOr only (round-7 lesson);
    //    idempotent => set semantics, duplicates collapse, deterministic.
    for (int i = blockIdx.x * 256 + tid; i < E; i += gthreads) {
        int r = e[i], c = e[E + i];
        atomicOr(&bitmap[(size_t)r * WPR + (c >> 5)], 1u << (c & 31));
    }
    grid.sync();

    // C: per-row degree + dinv-prescaled gemm  (ys = dinv * x @ W^T)
    for (int r = gw; r < N_NODES; r += gwaves)
        row_deg_gemm(r, lane, bitmap, x, Wt, ys);
    grid.sync();

    // D: per-row list-SpMM  (out = dinv*(ys[r] + sum ys[c]) + b)
    const float bl = bias[lane];
    for (int r = gw; r < N_NODES; r += gwaves)
        row_spmm(r, lane, bitmap, ys, bl, list[wave], out);
}

// ===========================================================================
// Fallback pipeline (4 launches) — same device functions, identical FP order.
// ===========================================================================
__global__ __launch_bounds__(256) void k_zero(uint4* __restrict__ bm4) {
    int i = blockIdx.x * 256 + threadIdx.x;
    bm4[i] = make_uint4(0u, 0u, 0u, 0u);
}

__global__ __launch_bounds__(256) void k_scatter(const int* __restrict__ e, int E,
                          unsigned* __restrict__ bitmap) {
    int i = (blockIdx.x * 256 + threadIdx.x) * 2;
    if (i + 1 < E) {
        int2 rr = *(const int2*)(e + i);
        int2 cc = *(const int2*)(e + E + i);
        atomicOr(&bitmap[(size_t)rr.x * WPR + (cc.x >> 5)], 1u << (cc.x & 31));
        atomicOr(&bitmap[(size_t)rr.y * WPR + (cc.y >> 5)], 1u << (cc.y & 31));
    } else if (i < E) {
        int r = e[i], c = e[E + i];
        atomicOr(&bitmap[(size_t)r * WPR + (c >> 5)], 1u << (c & 31));
    }
}

__global__ __launch_bounds__(256) void k_deg_gemm(const unsigned* __restrict__ bitmap,
                           const float* __restrict__ x,
                           const float* __restrict__ W,
                           float* __restrict__ ys) {
    __shared__ float Wt[C * C];
    int tid = threadIdx.x;
    for (int i = tid; i < C * C; i += 256) {
        int o = i >> 6, k = i & 63;
        Wt[k * C + o] = W[i];
    }
    __syncthreads();
    int r = blockIdx.x * 4 + (tid >> 6);
    row_deg_gemm(r, tid & 63, bitmap, x, Wt, ys);
}

__global__ __launch_bounds__(256) void k_spmm(const unsigned* __restrict__ bitmap,
                       const float* __restrict__ ys,
                       const float* __restrict__ bias,
                       float* __restrict__ out) {
    __shared__ unsigned short list[4][CAP];
    int wave = threadIdx.x >> 6, lane = threadIdx.x & 63;
    int r = blockIdx.x * 4 + wave;
    row_spmm(r, lane, bitmap, ys, bias[lane], list[wave], out);
}

// ===========================================================================
extern "C" void kernel_launch(void* const* d_in, const int* in_sizes, int n_in,
                              void* d_out, int out_size, void* d_ws, size_t ws_size,
                              hipStream_t stream) {
    const float* x  = (const float*)d_in[0];   // [8192, 64]
    const int*   ei = (const int*)d_in[1];     // [2, E] flat
    const float* W  = (const float*)d_in[2];   // [64, 64]
    const float* b  = (const float*)d_in[3];   // [64]
    float* out = (float*)d_out;                // [8192, 64]
    int E = in_sizes[1] / 2;

    // workspace layout: bitmap (8 MB) | ys (2 MB)
    unsigned* bitmap = (unsigned*)d_ws;
    float* ys = (float*)((char*)d_ws + (size_t)N_NODES * WPR * 4);

    // Host-only queries (stream-free => graph-capture-safe, deterministic).
    int dev = 0;           hipGetDevice(&dev);
    int coop = 0;          hipDeviceGetAttribute(&coop, hipDeviceAttributeCooperativeLaunch, dev);
    int cus = 0;           hipDeviceGetAttribute(&cus, hipDeviceAttributeMultiprocessorCount, dev);
    int maxBlkPerCU = 0;
    hipOccupancyMaxActiveBlocksPerMultiprocessor(&maxBlkPerCU, gcn_fused, 256, 0);

    bool done = false;
    if (coop && maxBlkPerCU > 0 && cus > 0) {
        int grid = maxBlkPerCU * cus;
        if (grid > MAXBLK) grid = MAXBLK;
        if (grid >= 64) {
            void* args[] = { (void*)&x, (void*)&ei, (void*)&E, (void*)&W,
                             (void*)&b, (void*)&bitmap, (void*)&ys, (void*)&out };
            hipError_t err = hipLaunchCooperativeKernel((const void*)gcn_fused,
                                dim3(grid), dim3(256), args, 0, stream);
            done = (err == hipSuccess);
        }
    }
    if (!done) {
        k_zero<<<N_NODES * WPR / 4 / 256, 256, 0, stream>>>((uint4*)bitmap);
        k_scatter<<<(E / 2 + 255) / 256, 256, 0, stream>>>(ei, E, bitmap);
        k_deg_gemm<<<N_NODES / 4, 256, 0, stream>>>(bitmap, x, W, ys);
        k_spmm<<<N_NODES / 4, 256, 0, stream>>>(bitmap, ys, b, out);
    }
}

// Round 11
// 50.305 us; speedup vs baseline: 3.9392x; 3.9392x over previous
//
#include <hip/hip_runtime.h>

#define N_NODES 8192
#define WPR 256      // 32-bit words per bitmap row (8192 bits)
#define C 64
#define CAP 512      // per-row neighbor-list capacity (avg degree ~32)

// ===========================================================================
// Per-row device functions (identical FP order to rounds 6/8 — validated).
// ===========================================================================

// --- one wave, one row: popcount -> dinv -> dinv-prescaled gemm ------------
__device__ __forceinline__ void row_deg_gemm(int r, int lane,
        const unsigned* __restrict__ bitmap, const float* __restrict__ x,
        const float* __restrict__ Wt, float* __restrict__ ys) {
    const uint4* row = (const uint4*)(bitmap + (size_t)r * WPR);
    uint4 v = row[lane];
    int cnt = __popc(v.x) + __popc(v.y) + __popc(v.z) + __popc(v.w);
#pragma unroll
    for (int off = 32; off; off >>= 1) cnt += __shfl_down(cnt, off);
    int total = __shfl(cnt, 0);
    // +1 = added eye; a self-loop bit is already in the popcount (diag 2.0),
    // matching the reference.
    float dr = rsqrtf((float)(total + 1));
    const float* xr = x + (size_t)r * C;
    float acc = 0.0f;
#pragma unroll
    for (int k = 0; k < C; ++k) acc += xr[k] * Wt[k * C + lane];
    ys[(size_t)r * C + lane] = dr * acc;
}

// --- one wave, one row: scan -> wave-private LDS list -> 8-way gather ------
__device__ __forceinline__ void row_spmm(int r, int lane,
        const unsigned* __restrict__ bitmap, const float* __restrict__ ys,
        float bl, unsigned short* __restrict__ L, float* __restrict__ out) {
    const uint4* row = (const uint4*)(bitmap + (size_t)r * WPR);
    uint4 v = row[lane];
    int myc = __popc(v.x) + __popc(v.y) + __popc(v.z) + __popc(v.w);
    int pre = myc;   // inclusive prefix sum over the wave
#pragma unroll
    for (int d = 1; d < 64; d <<= 1) {
        int t = __shfl_up(pre, d);
        if (lane >= d) pre += t;
    }
    int total = __shfl(pre, 63);
    int woff = pre - myc;
    float dr = rsqrtf((float)(total + 1));
    float acc = ys[(size_t)r * C + lane];   // eye term (ys is dinv-prescaled)
    if (total <= CAP) {
        int base = lane * 128;
        unsigned bits;
        bits = v.x; while (bits) { L[woff++] = (unsigned short)(base       + __builtin_ctz(bits)); bits &= bits - 1; }
        bits = v.y; while (bits) { L[woff++] = (unsigned short)(base + 32  + __builtin_ctz(bits)); bits &= bits - 1; }
        bits = v.z; while (bits) { L[woff++] = (unsigned short)(base + 64  + __builtin_ctz(bits)); bits &= bits - 1; }
        bits = v.w; while (bits) { L[woff++] = (unsigned short)(base + 96  + __builtin_ctz(bits)); bits &= bits - 1; }
        // no barrier: L is wave-private
        float a0=0.f,a1=0.f,a2=0.f,a3=0.f,a4=0.f,a5=0.f,a6=0.f,a7=0.f;
        int i = 0;
        for (; i + 8 <= total; i += 8) {
            int c0=L[i],  c1=L[i+1],c2=L[i+2],c3=L[i+3];
            int c4=L[i+4],c5=L[i+5],c6=L[i+6],c7=L[i+7];
            a0 += ys[(size_t)c0 * C + lane];
            a1 += ys[(size_t)c1 * C + lane];
            a2 += ys[(size_t)c2 * C + lane];
            a3 += ys[(size_t)c3 * C + lane];
            a4 += ys[(size_t)c4 * C + lane];
            a5 += ys[(size_t)c5 * C + lane];
            a6 += ys[(size_t)c6 * C + lane];
            a7 += ys[(size_t)c7 * C + lane];
        }
        for (; i < total; ++i) acc += ys[(size_t)L[i] * C + lane];
        acc += ((a0 + a1) + (a2 + a3)) + ((a4 + a5) + (a6 + a7));
    } else {
        // fallback: serial bitmap re-scan (correct for any degree)
        for (int w4i = 0; w4i < WPR / 4; ++w4i) {
            uint4 vv = row[w4i];
            int base = w4i * 128;
            unsigned bits;
            bits = vv.x; while (bits) { int c = base       + __builtin_ctz(bits); bits &= bits - 1; acc += ys[(size_t)c * C + lane]; }
            bits = vv.y; while (bits) { int c = base + 32  + __builtin_ctz(bits); bits &= bits - 1; acc += ys[(size_t)c * C + lane]; }
            bits = vv.z; while (bits) { int c = base + 64  + __builtin_ctz(bits); bits &= bits - 1; acc += ys[(size_t)c * C + lane]; }
            bits = vv.w; while (bits) { int c = base + 96  + __builtin_ctz(bits); bits &= bits - 1; acc += ys[(size_t)c * C + lane]; }
        }
    }
    out[(size_t)r * C + lane] = dr * acc + bl;
}

// ===========================================================================
// 4-launch pipeline. No cooperative launch (round 10: grid.sync() ~100 µs
// each on MI355X — 6x slower than the launch gaps it replaced).
// ===========================================================================
__global__ __launch_bounds__(256) void k_zero(uint4* __restrict__ bm4) {
    int i = blockIdx.x * 256 + threadIdx.x;
    bm4[i] = make_uint4(0u, 0u, 0u, 0u);
}

// NON-RETURNING atomicOr only (returning atomic + dependent atomicAdd was the
// round-7 regression). Idempotent => set semantics, duplicates collapse,
// deterministic. 2 edges/thread via int2.
__global__ __launch_bounds__(256) void k_scatter(const int* __restrict__ e, int E,
                          unsigned* __restrict__ bitmap) {
    int i = (blockIdx.x * 256 + threadIdx.x) * 2;
    if (i + 1 < E) {
        int2 rr = *(const int2*)(e + i);
        int2 cc = *(const int2*)(e + E + i);
        atomicOr(&bitmap[(size_t)rr.x * WPR + (cc.x >> 5)], 1u << (cc.x & 31));
        atomicOr(&bitmap[(size_t)rr.y * WPR + (cc.y >> 5)], 1u << (cc.y & 31));
    } else if (i < E) {
        int r = e[i], c = e[E + i];
        atomicOr(&bitmap[(size_t)r * WPR + (c >> 5)], 1u << (c & 31));
    }
}

// degree + prescaled gemm fused: ys[r] = rsqrt(deg[r]+1) * (x[r] @ W^T).
// W staged transposed in LDS => lane o reads Wt[k*64+o], conflict-free.
__global__ __launch_bounds__(256) void k_deg_gemm(const unsigned* __restrict__ bitmap,
                           const float* __restrict__ x,
                           const float* __restrict__ W,
                           float* __restrict__ ys) {
    __shared__ float Wt[C * C];
    int tid = threadIdx.x;
    for (int i = tid; i < C * C; i += 256) {
        int o = i >> 6, k = i & 63;
        Wt[k * C + o] = W[i];
    }
    __syncthreads();
    int r = blockIdx.x * 4 + (tid >> 6);
    row_deg_gemm(r, tid & 63, bitmap, x, Wt, ys);
}

// out[r] = dinv[r] * (ys[r] + sum_{c in row bits} ys[c]) + b
__global__ __launch_bounds__(256) void k_spmm(const unsigned* __restrict__ bitmap,
                       const float* __restrict__ ys,
                       const float* __restrict__ bias,
                       float* __restrict__ out) {
    __shared__ unsigned short list[4][CAP];
    int wave = threadIdx.x >> 6, lane = threadIdx.x & 63;
    int r = blockIdx.x * 4 + wave;
    row_spmm(r, lane, bitmap, ys, bias[lane], list[wave], out);
}

// ===========================================================================
extern "C" void kernel_launch(void* const* d_in, const int* in_sizes, int n_in,
                              void* d_out, int out_size, void* d_ws, size_t ws_size,
                              hipStream_t stream) {
    const float* x  = (const float*)d_in[0];   // [8192, 64]
    const int*   ei = (const int*)d_in[1];     // [2, E] flat
    const float* W  = (const float*)d_in[2];   // [64, 64]
    const float* b  = (const float*)d_in[3];   // [64]
    float* out = (float*)d_out;                // [8192, 64]
    int E = in_sizes[1] / 2;

    // workspace layout: bitmap (8 MB) | ys (2 MB)
    unsigned* bitmap = (unsigned*)d_ws;
    float* ys = (float*)((char*)d_ws + (size_t)N_NODES * WPR * 4);

    k_zero<<<N_NODES * WPR / 4 / 256, 256, 0, stream>>>((uint4*)bitmap);
    k_scatter<<<(E / 2 + 255) / 256, 256, 0, stream>>>(ei, E, bitmap);
    k_deg_gemm<<<N_NODES / 4, 256, 0, stream>>>(bitmap, x, W, ys);
    k_spmm<<<N_NODES / 4, 256, 0, stream>>>(bitmap, ys, b, out);
}